// Round 14
// baseline (550.673 us; speedup 1.0000x reference)
//
#include <hip/hip_runtime.h>
#include <math.h>

#define NB 8
#define NREG 64
#define DIM 1024
#define STRIPS 512               // segsum blocks; strip = ceil(N/STRIPS) <= 1024

typedef float f4 __attribute__((ext_vector_type(4)));

// ---------------- ws layout (bytes) ----------------
// sums    f32[64*1024]  @ 0        (262144)
// counts  u32[64]       @ 262144   (256)
// scores  f32[64]       @ 262400   (256)
// partial f4[64]        @ 262656   (1024)  per-block minmax {mnx,mny,mxx,mxy}
#define SUMS_OFF  0
#define CNT_OFF   262144
#define SCORE_OFF 262400
#define PART_OFF  262656

// K1: per-block coords minmax partials + zero accumulators + seed logit. grid 64.
__global__ __launch_bounds__(256) void k_minmax_init(const float2* __restrict__ coords,
                                                     int N,
                                                     float4* __restrict__ partial,
                                                     float* __restrict__ sums,
                                                     unsigned* __restrict__ counts,
                                                     float* __restrict__ scores,
                                                     float* __restrict__ out,
                                                     const float* __restrict__ c2_b) {
    int b = blockIdx.x, t = threadIdx.x;
    ((float4*)sums)[b * 256 + t] = make_float4(0.f, 0.f, 0.f, 0.f);
    if (b == 0) {
        if (t < NREG) { counts[t] = 0u; scores[t] = 0.f; }
        else if (t == 64) out[0] = c2_b[0];
    }
    float mnx = 1e30f, mny = 1e30f, mxx = -1e30f, mxy = -1e30f;
    for (int i = b * 256 + t; i < N; i += 64 * 256) {
        float2 c = coords[i];
        mnx = fminf(mnx, c.x); mny = fminf(mny, c.y);
        mxx = fmaxf(mxx, c.x); mxy = fmaxf(mxy, c.y);
    }
    for (int off = 32; off; off >>= 1) {
        mnx = fminf(mnx, __shfl_xor(mnx, off));
        mny = fminf(mny, __shfl_xor(mny, off));
        mxx = fmaxf(mxx, __shfl_xor(mxx, off));
        mxy = fmaxf(mxy, __shfl_xor(mxy, off));
    }
    __shared__ float s[4][4];
    int w = t >> 6, lane = t & 63;
    if (lane == 0) { s[w][0] = mnx; s[w][1] = mny; s[w][2] = mxx; s[w][3] = mxy; }
    __syncthreads();
    if (t == 0) {
        for (int i = 1; i < 4; ++i) {
            s[0][0] = fminf(s[0][0], s[i][0]);
            s[0][1] = fminf(s[0][1], s[i][1]);
            s[0][2] = fmaxf(s[0][2], s[i][2]);
            s[0][3] = fmaxf(s[0][3], s[i][3]);
        }
        partial[b] = make_float4(s[0][0], s[0][1], s[0][2], s[0][3]);
    }
}

// K2: dense-strip segment sum. Block owns contiguous rows [row0, row0+strip).
// rid inline + histogram (-> counts), in-LDS counting sort, 8-unrolled
// dwordx4 gather with register f4 accumulation, block-uniform run-boundary
// flush via 4 unsafeAtomicAdd.
#define FLUSHR(RR) do { float* dst_ = sums + (size_t)(RR) * DIM + 4 * t;        \
        unsafeAtomicAdd(dst_ + 0, acc.x); unsafeAtomicAdd(dst_ + 1, acc.y);     \
        unsafeAtomicAdd(dst_ + 2, acc.z); unsafeAtomicAdd(dst_ + 3, acc.w);     \
        acc = (f4)(0.f); } while (0)

__global__ __launch_bounds__(256) void k_segsum(const f4* __restrict__ x4,
                                                const float2* __restrict__ coords,
                                                int N, int strip,
                                                const float4* __restrict__ partial,
                                                unsigned* __restrict__ counts,
                                                float* __restrict__ sums) {
    __shared__ float prm[4];                 // lox, loy, spx, spy
    __shared__ unsigned cnt[NREG];
    __shared__ unsigned cur[NREG];
    __shared__ unsigned char srid[1024];
    __shared__ unsigned list[1025];          // p | (r<<16), sorted by r; +sentinel
    int t = threadIdx.x;
    int row0 = blockIdx.x * strip;
    int nrows = min(N - row0, strip);
    if (nrows <= 0) return;

    if (t < NREG) cnt[t] = 0u;
    if (t < 64) {
        float4 p = partial[t];
        float mnx = p.x, mny = p.y, mxx = p.z, mxy = p.w;
        for (int off = 32; off; off >>= 1) {
            mnx = fminf(mnx, __shfl_xor(mnx, off));
            mny = fminf(mny, __shfl_xor(mny, off));
            mxx = fmaxf(mxx, __shfl_xor(mxx, off));
            mxy = fmaxf(mxy, __shfl_xor(mxy, off));
        }
        if (t == 0) {
            prm[0] = mnx; prm[1] = mny;
            prm[2] = fmaxf(mxx - mnx, 1.0f);
            prm[3] = fmaxf(mxy - mny, 1.0f);
        }
    }
    __syncthreads();

    for (int p = t; p < nrows; p += 256) {
        float2 c = coords[row0 + p];
        float qx = ((c.x - prm[0]) / prm[2]) * (float)NB;
        float qy = ((c.y - prm[1]) / prm[3]) * (float)NB;
        int bx = min(max((int)qx, 0), NB - 1);
        int by = min(max((int)qy, 0), NB - 1);
        int r = by * NB + bx;
        srid[p] = (unsigned char)r;
        atomicAdd(&cnt[r], 1u);
    }
    __syncthreads();
    if (t < NREG && cnt[t]) atomicAdd(&counts[t], cnt[t]);
    if (t == 0) {
        unsigned run = 0;
        for (int i = 0; i < NREG; ++i) { cur[i] = run; run += cnt[i]; }
        list[nrows] = 0xFFFF0000u;           // sentinel region
    }
    __syncthreads();
    for (int p = t; p < nrows; p += 256) {
        unsigned r = srid[p];
        unsigned pos = atomicAdd(&cur[r], 1u);
        list[pos] = (unsigned)p | (r << 16);
    }
    __syncthreads();

    const f4* xb = x4 + (size_t)row0 * (DIM / 4) + t;
    f4 acc = (f4)(0.f);
    int j = 0;
    for (; j + 8 <= nrows; j += 8) {
        unsigned e0 = list[j + 0], e1 = list[j + 1], e2 = list[j + 2], e3 = list[j + 3];
        unsigned e4 = list[j + 4], e5 = list[j + 5], e6 = list[j + 6], e7 = list[j + 7];
        unsigned e8r = list[j + 8] >> 16;    // next entry or sentinel
        f4 v0 = xb[(size_t)(e0 & 0xFFFFu) * (DIM / 4)];
        f4 v1 = xb[(size_t)(e1 & 0xFFFFu) * (DIM / 4)];
        f4 v2 = xb[(size_t)(e2 & 0xFFFFu) * (DIM / 4)];
        f4 v3 = xb[(size_t)(e3 & 0xFFFFu) * (DIM / 4)];
        f4 v4 = xb[(size_t)(e4 & 0xFFFFu) * (DIM / 4)];
        f4 v5 = xb[(size_t)(e5 & 0xFFFFu) * (DIM / 4)];
        f4 v6 = xb[(size_t)(e6 & 0xFFFFu) * (DIM / 4)];
        f4 v7 = xb[(size_t)(e7 & 0xFFFFu) * (DIM / 4)];
        acc += v0; if ((e0 >> 16) != (e1 >> 16)) FLUSHR(e0 >> 16);
        acc += v1; if ((e1 >> 16) != (e2 >> 16)) FLUSHR(e1 >> 16);
        acc += v2; if ((e2 >> 16) != (e3 >> 16)) FLUSHR(e2 >> 16);
        acc += v3; if ((e3 >> 16) != (e4 >> 16)) FLUSHR(e3 >> 16);
        acc += v4; if ((e4 >> 16) != (e5 >> 16)) FLUSHR(e4 >> 16);
        acc += v5; if ((e5 >> 16) != (e6 >> 16)) FLUSHR(e5 >> 16);
        acc += v6; if ((e6 >> 16) != (e7 >> 16)) FLUSHR(e6 >> 16);
        acc += v7; if ((e7 >> 16) != e8r)        FLUSHR(e7 >> 16);
    }
    for (; j < nrows; ++j) {
        unsigned e = list[j];
        f4 v = xb[(size_t)(e & 0xFFFFu) * (DIM / 4)];
        acc += v;
        if ((e >> 16) != (list[j + 1] >> 16)) FLUSHR(e >> 16);
    }
}

// K3: gated attention scores, barrier-free: warp w owns attention row a.
// grid = 64 blocks: (a-quad 0..31) x (reg-half 0..1).
__global__ __launch_bounds__(256) void k_scores(const float* __restrict__ sums,
                                                const unsigned* __restrict__ counts,
                                                const float* __restrict__ U_w,
                                                const float* __restrict__ U_b,
                                                const float* __restrict__ V_w,
                                                const float* __restrict__ V_b,
                                                const float* __restrict__ w_w,
                                                float* __restrict__ scores) {
    __shared__ float Us[4][DIM];
    __shared__ float Vs[4][DIM];
    int t = threadIdx.x, w = t >> 6, lane = t & 63;
    int q = blockIdx.x >> 1;
    int h = blockIdx.x & 1;
    int a = q * 4 + w;
    const float4* U4 = (const float4*)(U_w + (size_t)a * DIM);
    const float4* V4 = (const float4*)(V_w + (size_t)a * DIM);
    #pragma unroll
    for (int s = 0; s < 4; ++s) {
        ((float4*)Us[w])[s * 64 + lane] = U4[s * 64 + lane];
        ((float4*)Vs[w])[s * 64 + lane] = V4[s * 64 + lane];
    }
    float ub = U_b[a], vb = V_b[a], ww = w_w[a];
    int r0 = h * 32;
    for (int reg = r0; reg < r0 + 32; ++reg) {
        float inv = 1.0f / fmaxf((float)counts[reg], 1.0f);
        float du = 0.f, dv = 0.f;
        #pragma unroll
        for (int s = 0; s < 4; ++s) {
            float4 sv = ((const float4*)(sums + (size_t)reg * DIM))[s * 64 + lane];
            float4 u4 = ((const float4*)Us[w])[s * 64 + lane];
            float4 v4 = ((const float4*)Vs[w])[s * 64 + lane];
            float rx = sv.x * inv, ry = sv.y * inv, rz = sv.z * inv, rw = sv.w * inv;
            du = fmaf(u4.x, rx, fmaf(u4.y, ry, fmaf(u4.z, rz, fmaf(u4.w, rw, du))));
            dv = fmaf(v4.x, rx, fmaf(v4.y, ry, fmaf(v4.z, rz, fmaf(v4.w, rw, dv))));
        }
        for (int off = 32; off; off >>= 1) {
            du += __shfl_xor(du, off);
            dv += __shfl_xor(dv, off);
        }
        if (lane == 0) {
            float g = tanhf(du + ub) * (1.0f / (1.0f + expf(-(dv + vb))));
            unsafeAtomicAdd(&scores[reg], ww * g);
        }
    }
}

// K4: softmax over 64 scores (redundant per block); slide slice of 64 cols.
__global__ __launch_bounds__(256) void k_attn_slide(const float* __restrict__ scores,
                                                    const unsigned* __restrict__ counts,
                                                    const float* __restrict__ sums,
                                                    float* __restrict__ out) {
    __shared__ float coef[NREG];
    __shared__ float partial[4][64];
    int t = threadIdx.x;
    if (t < 64) {
        unsigned cnt = counts[t];
        float sc = (cnt > 0u) ? scores[t] : -INFINITY;
        float m = sc;
        for (int off = 32; off; off >>= 1) m = fmaxf(m, __shfl_xor(m, off));
        float e = expf(sc - m);
        float sum = e;
        for (int off = 32; off; off >>= 1) sum += __shfl_xor(sum, off);
        float a = e / sum;
        if (blockIdx.x == 0) out[1 + DIM + t] = a;
        coef[t] = a / fmaxf((float)cnt, 1.0f);
    }
    __syncthreads();
    int lane = t & 63, rg = t >> 6;
    int d = blockIdx.x * 64 + lane;
    float acc = 0.f;
    #pragma unroll
    for (int rr = 0; rr < 16; ++rr) {
        int reg = rg * 16 + rr;
        acc = fmaf(coef[reg], sums[(size_t)reg * DIM + d], acc);
    }
    partial[rg][lane] = acc;
    __syncthreads();
    if (t < 64)
        out[1 + blockIdx.x * 64 + t] =
            partial[0][t] + partial[1][t] + partial[2][t] + partial[3][t];
}

// K5: h = relu(c1_w @ slide + c1_b); logit += c2_w . h
__global__ __launch_bounds__(256) void k_classifier(const float* __restrict__ c1_w,
                                                    const float* __restrict__ c1_b,
                                                    const float* __restrict__ c2_w,
                                                    const float* __restrict__ slide,
                                                    float* __restrict__ out) {
    int w = threadIdx.x >> 6, lane = threadIdx.x & 63;
    int j = blockIdx.x * 4 + w;
    const float* cw = c1_w + (size_t)j * DIM;
    float acc = 0.f;
    #pragma unroll
    for (int jj = 0; jj < 16; ++jj) {
        int d = lane + jj * 64;
        acc = fmaf(cw[d], slide[d], acc);
    }
    for (int off = 32; off; off >>= 1) acc += __shfl_xor(acc, off);
    __shared__ float sp[4];
    if (lane == 0) sp[w] = fmaxf(acc + c1_b[j], 0.f) * c2_w[j];
    __syncthreads();
    if (threadIdx.x == 0) unsafeAtomicAdd(&out[0], sp[0] + sp[1] + sp[2] + sp[3]);
}

extern "C" void kernel_launch(void* const* d_in, const int* in_sizes, int n_in,
                              void* d_out, int out_size, void* d_ws, size_t ws_size,
                              hipStream_t stream) {
    const float*  x      = (const float*)d_in[0];
    const float2* coords = (const float2*)d_in[1];
    const float*  U_w    = (const float*)d_in[2];
    const float*  U_b    = (const float*)d_in[3];
    const float*  V_w    = (const float*)d_in[4];
    const float*  V_b    = (const float*)d_in[5];
    const float*  w_w    = (const float*)d_in[6];
    const float*  c1_w   = (const float*)d_in[7];
    const float*  c1_b   = (const float*)d_in[8];
    const float*  c2_w   = (const float*)d_in[9];
    const float*  c2_b   = (const float*)d_in[10];
    int N = in_sizes[0] / DIM;

    float* out = (float*)d_out;
    char* ws = (char*)d_ws;
    float*    sums    = (float*)(ws + SUMS_OFF);
    unsigned* counts  = (unsigned*)(ws + CNT_OFF);
    float*    scores  = (float*)(ws + SCORE_OFF);
    float4*   partial = (float4*)(ws + PART_OFF);

    int strip = (N + STRIPS - 1) / STRIPS;    // ~196; <= 1024 for N <= 524288

    hipLaunchKernelGGL(k_minmax_init, dim3(64), dim3(256), 0, stream,
                       coords, N, partial, sums, counts, scores, out, c2_b);
    hipLaunchKernelGGL(k_segsum, dim3(STRIPS), dim3(256), 0, stream,
                       (const f4*)x, coords, N, strip, partial, counts, sums);
    hipLaunchKernelGGL(k_scores, dim3(64), dim3(256), 0, stream,
                       sums, counts, U_w, U_b, V_w, V_b, w_w, scores);
    hipLaunchKernelGGL(k_attn_slide, dim3(16), dim3(256), 0, stream,
                       scores, counts, sums, out);
    hipLaunchKernelGGL(k_classifier, dim3(NREG), dim3(256), 0, stream,
                       c1_w, c1_b, c2_w, out + 1, out);
}

// Round 15
// 158.504 us; speedup vs baseline: 3.4742x; 3.4742x over previous
//
#include <hip/hip_runtime.h>
#include <math.h>

#define NB 8
#define NREG 64
#define DIM 1024
#define ADIM 128
#define SUBB 32                  // gather sub-blocks per region in segsum

typedef float f4 __attribute__((ext_vector_type(4)));

// ---------------- ws layout (bytes) ----------------
// sums    f32[64*1024]  @ 0        (262144)
// cursor  u32[64]       @ 262144   (256)   == counts after scatter
// scores  f32[64]       @ 262400   (256)
// partial f4[64]        @ 262656   (1024)  per-block minmax {mnx,mny,mxx,mxy}
// slot    u32[64*CAP]   @ 263680   (~25.6 MB)
#define SUMS_OFF  0
#define CUR_OFF   262144
#define SCORE_OFF 262400
#define PART_OFF  262656
#define SLOT_OFF  263680

// K1: per-block coords minmax partials + zero accumulators + seed logit. grid 64.
__global__ __launch_bounds__(256) void k_minmax_init(const float2* __restrict__ coords,
                                                     int N,
                                                     float4* __restrict__ partial,
                                                     float* __restrict__ sums,
                                                     unsigned* __restrict__ cursor,
                                                     float* __restrict__ scores,
                                                     float* __restrict__ out,
                                                     const float* __restrict__ c2_b) {
    int b = blockIdx.x, t = threadIdx.x;
    ((float4*)sums)[b * 256 + t] = make_float4(0.f, 0.f, 0.f, 0.f);
    if (b == 0) {
        if (t < NREG) { cursor[t] = 0u; scores[t] = 0.f; }
        else if (t == 64) out[0] = c2_b[0];
    }
    float mnx = 1e30f, mny = 1e30f, mxx = -1e30f, mxy = -1e30f;
    for (int i = b * 256 + t; i < N; i += 64 * 256) {
        float2 c = coords[i];
        mnx = fminf(mnx, c.x); mny = fminf(mny, c.y);
        mxx = fmaxf(mxx, c.x); mxy = fmaxf(mxy, c.y);
    }
    for (int off = 32; off; off >>= 1) {
        mnx = fminf(mnx, __shfl_xor(mnx, off));
        mny = fminf(mny, __shfl_xor(mny, off));
        mxx = fmaxf(mxx, __shfl_xor(mxx, off));
        mxy = fmaxf(mxy, __shfl_xor(mxy, off));
    }
    __shared__ float s[4][4];
    int w = t >> 6, lane = t & 63;
    if (lane == 0) { s[w][0] = mnx; s[w][1] = mny; s[w][2] = mxx; s[w][3] = mxy; }
    __syncthreads();
    if (t == 0) {
        for (int i = 1; i < 4; ++i) {
            s[0][0] = fminf(s[0][0], s[i][0]);
            s[0][1] = fminf(s[0][1], s[i][1]);
            s[0][2] = fmaxf(s[0][2], s[i][2]);
            s[0][3] = fmaxf(s[0][3], s[i][3]);
        }
        partial[b] = make_float4(s[0][0], s[0][1], s[0][2], s[0][3]);
    }
}

// K2: reduce minmax partials in-block, then scatter indices into per-region slots.
__global__ __launch_bounds__(256) void k_scatter(const float2* __restrict__ coords, int N,
                                                 const float4* __restrict__ partial,
                                                 unsigned* __restrict__ cursor,
                                                 unsigned* __restrict__ slot, int cap) {
    __shared__ float prm[4];          // lox, loy, spx, spy
    __shared__ unsigned lreg[NREG];
    __shared__ unsigned gbase[NREG];
    int t = threadIdx.x;
    if (t < NREG) lreg[t] = 0u;
    if (t < 64) {
        float4 p = partial[t];
        float mnx = p.x, mny = p.y, mxx = p.z, mxy = p.w;
        for (int off = 32; off; off >>= 1) {
            mnx = fminf(mnx, __shfl_xor(mnx, off));
            mny = fminf(mny, __shfl_xor(mny, off));
            mxx = fmaxf(mxx, __shfl_xor(mxx, off));
            mxy = fmaxf(mxy, __shfl_xor(mxy, off));
        }
        if (t == 0) {
            prm[0] = mnx; prm[1] = mny;
            prm[2] = fmaxf(mxx - mnx, 1.0f);
            prm[3] = fmaxf(mxy - mny, 1.0f);
        }
    }
    __syncthreads();
    int i = blockIdx.x * 256 + t;
    int r = 0; unsigned rank = 0;
    if (i < N) {
        float2 c = coords[i];
        float qx = ((c.x - prm[0]) / prm[2]) * (float)NB;
        float qy = ((c.y - prm[1]) / prm[3]) * (float)NB;
        int bx = min(max((int)qx, 0), NB - 1);
        int by = min(max((int)qy, 0), NB - 1);
        r = by * NB + bx;
        rank = atomicAdd(&lreg[r], 1u);
    }
    __syncthreads();
    if (t < NREG) gbase[t] = lreg[t] ? atomicAdd(&cursor[t], lreg[t]) : 0u;
    __syncthreads();
    if (i < N) slot[(size_t)r * cap + gbase[r] + rank] = (unsigned)i;
}

// K3: segment sum. grid = 64 regions x SUBB sub-blocks (region = bid&63);
// register accumulation, single atomic flush, plain (cached) loads.
__global__ __launch_bounds__(256) void k_segsum(const f4* __restrict__ x4,
                                                const unsigned* __restrict__ slot,
                                                const unsigned* __restrict__ cursor,
                                                int cap,
                                                float* __restrict__ sums) {
    int t = threadIdx.x;
    int r = blockIdx.x & 63;
    int k = blockIdx.x >> 6;
    int cnt = (int)cursor[r];
    int chunk = ((((cnt + SUBB - 1) / SUBB) + 7) & ~7);   // multiple of 8
    int j0 = k * chunk;
    int j1 = min(cnt, j0 + chunk);
    const unsigned* sl = slot + (size_t)r * cap;

    f4 acc = (f4)(0.f);
    int j = j0;
    for (; j + 8 <= j1; j += 8) {
        uint4 ia = *(const uint4*)(sl + j);
        uint4 ib = *(const uint4*)(sl + j + 4);
        f4 v0 = x4[(size_t)ia.x * (DIM / 4) + t];
        f4 v1 = x4[(size_t)ia.y * (DIM / 4) + t];
        f4 v2 = x4[(size_t)ia.z * (DIM / 4) + t];
        f4 v3 = x4[(size_t)ia.w * (DIM / 4) + t];
        f4 v4 = x4[(size_t)ib.x * (DIM / 4) + t];
        f4 v5 = x4[(size_t)ib.y * (DIM / 4) + t];
        f4 v6 = x4[(size_t)ib.z * (DIM / 4) + t];
        f4 v7 = x4[(size_t)ib.w * (DIM / 4) + t];
        acc += v0; acc += v1; acc += v2; acc += v3;
        acc += v4; acc += v5; acc += v6; acc += v7;
    }
    for (; j < j1; ++j) {
        f4 v = x4[(size_t)sl[j] * (DIM / 4) + t];
        acc += v;
    }
    if (j1 > j0) {
        float* dst = sums + (size_t)r * DIM + 4 * t;
        unsafeAtomicAdd(dst + 0, acc.x);
        unsafeAtomicAdd(dst + 1, acc.y);
        unsafeAtomicAdd(dst + 2, acc.z);
        unsafeAtomicAdd(dst + 3, acc.w);
    }
}

// K4: gated attention scores, barrier-free: warp w owns attention row a.
// grid = 64 blocks: (a-quad 0..31) x (reg-half 0..1).
__global__ __launch_bounds__(256) void k_scores(const float* __restrict__ sums,
                                                const unsigned* __restrict__ counts,
                                                const float* __restrict__ U_w,
                                                const float* __restrict__ U_b,
                                                const float* __restrict__ V_w,
                                                const float* __restrict__ V_b,
                                                const float* __restrict__ w_w,
                                                float* __restrict__ scores) {
    __shared__ float Us[4][DIM];
    __shared__ float Vs[4][DIM];
    int t = threadIdx.x, w = t >> 6, lane = t & 63;
    int q = blockIdx.x >> 1;
    int h = blockIdx.x & 1;
    int a = q * 4 + w;
    const float4* U4 = (const float4*)(U_w + (size_t)a * DIM);
    const float4* V4 = (const float4*)(V_w + (size_t)a * DIM);
    #pragma unroll
    for (int s = 0; s < 4; ++s) {
        ((float4*)Us[w])[s * 64 + lane] = U4[s * 64 + lane];
        ((float4*)Vs[w])[s * 64 + lane] = V4[s * 64 + lane];
    }
    float ub = U_b[a], vb = V_b[a], ww = w_w[a];
    int r0 = h * 32;
    for (int reg = r0; reg < r0 + 32; ++reg) {
        float inv = 1.0f / fmaxf((float)counts[reg], 1.0f);
        float du = 0.f, dv = 0.f;
        #pragma unroll
        for (int s = 0; s < 4; ++s) {
            float4 sv = ((const float4*)(sums + (size_t)reg * DIM))[s * 64 + lane];
            float4 u4 = ((const float4*)Us[w])[s * 64 + lane];
            float4 v4 = ((const float4*)Vs[w])[s * 64 + lane];
            float rx = sv.x * inv, ry = sv.y * inv, rz = sv.z * inv, rw = sv.w * inv;
            du = fmaf(u4.x, rx, fmaf(u4.y, ry, fmaf(u4.z, rz, fmaf(u4.w, rw, du))));
            dv = fmaf(v4.x, rx, fmaf(v4.y, ry, fmaf(v4.z, rz, fmaf(v4.w, rw, dv))));
        }
        for (int off = 32; off; off >>= 1) {
            du += __shfl_xor(du, off);
            dv += __shfl_xor(dv, off);
        }
        if (lane == 0) {
            float g = tanhf(du + ub) * (1.0f / (1.0f + expf(-(dv + vb))));
            unsafeAtomicAdd(&scores[reg], ww * g);
        }
    }
}

// K5: softmax over 64 scores (redundant per block); slide slice of 64 cols.
// grid = 16 blocks. Writes attn (block 0) and slide to out[1..1024].
__global__ __launch_bounds__(256) void k_attn_slide(const float* __restrict__ scores,
                                                    const unsigned* __restrict__ counts,
                                                    const float* __restrict__ sums,
                                                    float* __restrict__ out) {
    __shared__ float coef[NREG];
    __shared__ float partial[4][64];
    int t = threadIdx.x;
    if (t < 64) {
        unsigned cnt = counts[t];
        float sc = (cnt > 0u) ? scores[t] : -INFINITY;
        float m = sc;
        for (int off = 32; off; off >>= 1) m = fmaxf(m, __shfl_xor(m, off));
        float e = expf(sc - m);
        float sum = e;
        for (int off = 32; off; off >>= 1) sum += __shfl_xor(sum, off);
        float a = e / sum;
        if (blockIdx.x == 0) out[1 + DIM + t] = a;
        coef[t] = a / fmaxf((float)cnt, 1.0f);
    }
    __syncthreads();
    int lane = t & 63, rg = t >> 6;
    int d = blockIdx.x * 64 + lane;
    float acc = 0.f;
    #pragma unroll
    for (int rr = 0; rr < 16; ++rr) {
        int reg = rg * 16 + rr;
        acc = fmaf(coef[reg], sums[(size_t)reg * DIM + d], acc);
    }
    partial[rg][lane] = acc;
    __syncthreads();
    if (t < 64)
        out[1 + blockIdx.x * 64 + t] =
            partial[0][t] + partial[1][t] + partial[2][t] + partial[3][t];
}

// K6: h = relu(c1_w @ slide + c1_b); logit += c2_w . h  (slide read from out+1)
__global__ __launch_bounds__(256) void k_classifier(const float* __restrict__ c1_w,
                                                    const float* __restrict__ c1_b,
                                                    const float* __restrict__ c2_w,
                                                    const float* __restrict__ slide,
                                                    float* __restrict__ out) {
    int w = threadIdx.x >> 6, lane = threadIdx.x & 63;
    int j = blockIdx.x * 4 + w;
    const float* cw = c1_w + (size_t)j * DIM;
    float acc = 0.f;
    #pragma unroll
    for (int jj = 0; jj < 16; ++jj) {
        int d = lane + jj * 64;
        acc = fmaf(cw[d], slide[d], acc);
    }
    for (int off = 32; off; off >>= 1) acc += __shfl_xor(acc, off);
    __shared__ float sp[4];
    if (lane == 0) sp[w] = fmaxf(acc + c1_b[j], 0.f) * c2_w[j];
    __syncthreads();
    if (threadIdx.x == 0) unsafeAtomicAdd(&out[0], sp[0] + sp[1] + sp[2] + sp[3]);
}

extern "C" void kernel_launch(void* const* d_in, const int* in_sizes, int n_in,
                              void* d_out, int out_size, void* d_ws, size_t ws_size,
                              hipStream_t stream) {
    const float*  x      = (const float*)d_in[0];
    const float2* coords = (const float2*)d_in[1];
    const float*  U_w    = (const float*)d_in[2];
    const float*  U_b    = (const float*)d_in[3];
    const float*  V_w    = (const float*)d_in[4];
    const float*  V_b    = (const float*)d_in[5];
    const float*  w_w    = (const float*)d_in[6];
    const float*  c1_w   = (const float*)d_in[7];
    const float*  c1_b   = (const float*)d_in[8];
    const float*  c2_w   = (const float*)d_in[9];
    const float*  c2_b   = (const float*)d_in[10];
    int N = in_sizes[0] / DIM;

    float* out = (float*)d_out;
    char* ws = (char*)d_ws;
    float*    sums    = (float*)(ws + SUMS_OFF);
    unsigned* cursor  = (unsigned*)(ws + CUR_OFF);
    float*    scores  = (float*)(ws + SCORE_OFF);
    float4*   partial = (float4*)(ws + PART_OFF);
    unsigned* slot    = (unsigned*)(ws + SLOT_OFF);
    int cap = (N + 7) & ~7;

    hipLaunchKernelGGL(k_minmax_init, dim3(64), dim3(256), 0, stream,
                       coords, N, partial, sums, cursor, scores, out, c2_b);
    hipLaunchKernelGGL(k_scatter, dim3((N + 255) / 256), dim3(256), 0, stream,
                       coords, N, partial, cursor, slot, cap);
    hipLaunchKernelGGL(k_segsum, dim3(NREG * SUBB), dim3(256), 0, stream,
                       (const f4*)x, slot, cursor, cap, sums);
    hipLaunchKernelGGL(k_scores, dim3(64), dim3(256), 0, stream,
                       sums, cursor, U_w, U_b, V_w, V_b, w_w, scores);
    hipLaunchKernelGGL(k_attn_slide, dim3(16), dim3(256), 0, stream,
                       scores, cursor, sums, out);
    hipLaunchKernelGGL(k_classifier, dim3(NREG), dim3(256), 0, stream,
                       c1_w, c1_b, c2_w, out + 1, out);
}